// Round 7
// baseline (441.463 us; speedup 1.0000x reference)
//
#include <hip/hip_runtime.h>

// GCN 2-layer. R7: gathers restructured — chunked edge preload + readlane
// broadcast (edge decode on SALU, parallel to VALU), 3-op weight codec
// (float bits[26:12]), gather64 uses ushort lanes (1 bf16 feat/lane),
// u32 indexing everywhere in the hot loops.
// R6 carry-over: bf16-MFMA GEMMs (operand-swap epilogue), bf16 feature
// storage, atomic-free CSR placement, multi-block scan.

typedef unsigned int u32;
typedef unsigned short u16;
using bfrag = __attribute__((ext_vector_type(8))) short;   // 8 bf16 (4 VGPRs)
using f4    = __attribute__((ext_vector_type(4))) float;   // 4 fp32 acc

__device__ inline u32 pack_bf16(float a, float b) {
    u32 ua = __float_as_uint(a);
    u32 ub = __float_as_uint(b);
    ua += 0x7fffu + ((ua >> 16) & 1u);   // RNE
    ub += 0x7fffu + ((ub >> 16) & 1u);
    return (ua >> 16) | (ub & 0xffff0000u);
}
__device__ inline float bf_lo(u32 v) { return __uint_as_float(v << 16); }
__device__ inline float bf_hi(u32 v) { return __uint_as_float(v & 0xffff0000u); }

// w in [2^-15, 2): store float bits[26:12] (15 b). Decode = shl+and+or.
__device__ inline u32 pack_w(float w) {
    u32 b = __float_as_uint(w) + 0x800u;   // RNE to 11-bit mantissa
    if (b < 0x38000000u) b = 0x38000000u;  // clamp (unreachable for our degs)
    return (b >> 12) & 0x7fffu;
}
__device__ inline float dec_w(u32 e) {
    return __uint_as_float(0x38000000u | ((e & 0x7fffu) << 12));
}

__device__ inline bfrag as_bfrag(uint4 v) {
    union { uint4 u; bfrag b; } x; x.u = v; return x.b;
}

__global__ void zero_i32(int* __restrict__ p, int n) {
    int i = blockIdx.x * blockDim.x + threadIdx.x;
    if (i < n) p[i] = 0;
}

__global__ void hist_rank(const int* __restrict__ dst, int* __restrict__ cnt,
                          int* __restrict__ rank, int E) {
    int e = blockIdx.x * blockDim.x + threadIdx.x;
    if (e < E) rank[e] = atomicAdd(&cnt[dst[e]], 1);
}

__global__ __launch_bounds__(1024) void scan_reduce(const int* __restrict__ cnt,
                                                    int* __restrict__ bsum, int n) {
    __shared__ int wsum[16];
    int i = blockIdx.x * 1024 + threadIdx.x;
    int v = (i < n) ? cnt[i] : 0;
#pragma unroll
    for (int off = 32; off > 0; off >>= 1) v += __shfl_down(v, off);
    const int lane = threadIdx.x & 63;
    const int wid  = threadIdx.x >> 6;
    if (lane == 0) wsum[wid] = v;
    __syncthreads();
    if (threadIdx.x < 16) {
        int s = wsum[threadIdx.x];
#pragma unroll
        for (int off = 8; off > 0; off >>= 1) s += __shfl_down(s, off);
        if (threadIdx.x == 0) bsum[blockIdx.x] = s;
    }
}

__global__ void scan_partials(const int* __restrict__ bsum, int* __restrict__ boff,
                              int* __restrict__ row_ptr, int nb, int n) {
    const int lane = threadIdx.x;  // 64 threads
    int carry = 0;
    for (int base = 0; base < nb; base += 64) {
        int i = base + lane;
        int v = (i < nb) ? bsum[i] : 0;
        int x = v;
#pragma unroll
        for (int off = 1; off < 64; off <<= 1) {
            int t = __shfl_up(x, off);
            if (lane >= off) x += t;
        }
        if (i < nb) boff[i] = carry + x - v;
        carry += __shfl(x, 63);
    }
    if (lane == 0) row_ptr[n] = carry;
}

__global__ __launch_bounds__(1024) void scan_apply(const int* __restrict__ cnt,
                                                   const int* __restrict__ boff,
                                                   int* __restrict__ row_ptr,
                                                   float* __restrict__ dinv, int n) {
    __shared__ int wsum[16];
    const int lane = threadIdx.x & 63;
    const int wid  = threadIdx.x >> 6;
    int i = blockIdx.x * 1024 + threadIdx.x;
    int v = (i < n) ? cnt[i] : 0;
    int x = v;
#pragma unroll
    for (int off = 1; off < 64; off <<= 1) {
        int t = __shfl_up(x, off);
        if (lane >= off) x += t;
    }
    if (lane == 63) wsum[wid] = x;
    __syncthreads();
    if (wid == 0 && lane < 16) {
        int w = wsum[lane];
#pragma unroll
        for (int off = 1; off < 16; off <<= 1) {
            int t = __shfl_up(w, off);
            if (lane >= off) w += t;
        }
        wsum[lane] = w;
    }
    __syncthreads();
    int wave_excl = (wid == 0) ? 0 : wsum[wid - 1];
    if (i < n) {
        row_ptr[i] = boff[blockIdx.x] + wave_excl + (x - v);
        dinv[i]    = rsqrtf((float)v + 1.0f);
    }
}

__global__ void place_csr(const int* __restrict__ src, const int* __restrict__ dst,
                          const int* __restrict__ rank, const int* __restrict__ row_ptr,
                          const float* __restrict__ dinv, u32* __restrict__ ew, int E) {
    int e = blockIdx.x * blockDim.x + threadIdx.x;
    if (e < E) {
        int s = src[e];
        int d = dst[e];
        float w = dinv[s] * dinv[d];
        ew[row_ptr[d] + rank[e]] = ((u32)s << 15) | pack_w(w);
    }
}

// W1[128][128], W2[128][64] fp32 -> Wt bf16-pair packed, transposed.
__global__ void prep_w(const float* __restrict__ W1, const float* __restrict__ W2,
                       u32* __restrict__ W1t, u32* __restrict__ W2t) {
    int idx = blockIdx.x * 256 + threadIdx.x;
    if (idx < 128 * 64) {
        int nr = idx >> 6, kd = idx & 63;
        W1t[idx] = pack_bf16(W1[(2 * kd) * 128 + nr], W1[(2 * kd + 1) * 128 + nr]);
    } else if (idx < 128 * 64 + 64 * 64) {
        int i = idx - 128 * 64;
        int nr = i >> 6, kd = i & 63;
        W2t[i] = pack_bf16(W2[(2 * kd) * 64 + nr], W2[(2 * kd + 1) * 64 + nr]);
    }
}

// C[n][OUT] bf16-packed = A[n][128] @ W[128][OUT], via 16x16x32 bf16 MFMA.
template <int OUT, bool ABF>
__global__ __launch_bounds__(256) void gemm_mfma(const void* __restrict__ Ap,
                                                 const u32* __restrict__ Wt,
                                                 u32* __restrict__ C, int n) {
    constexpr int NT = OUT / 16;
    const int lane = threadIdx.x & 63;
    const int wv   = threadIdx.x >> 6;
    const int r15  = lane & 15;
    const int quad = lane >> 4;
    const int rowbase = blockIdx.x * 128 + wv * 32;

    bfrag af[2][4];
#pragma unroll
    for (int mi = 0; mi < 2; ++mi) {
        int row = rowbase + mi * 16 + r15;
        row = (row < n) ? row : (n - 1);
        if constexpr (ABF) {
            const u32* ar = (const u32*)Ap + (size_t)row * 64 + quad * 4;
#pragma unroll
            for (int ks = 0; ks < 4; ++ks)
                af[mi][ks] = as_bfrag(*(const uint4*)(ar + ks * 16));
        } else {
            const float* arf = (const float*)Ap + (size_t)row * 128 + quad * 8;
#pragma unroll
            for (int ks = 0; ks < 4; ++ks) {
                float4 v0 = *(const float4*)(arf + ks * 32);
                float4 v1 = *(const float4*)(arf + ks * 32 + 4);
                uint4 p;
                p.x = pack_bf16(v0.x, v0.y);
                p.y = pack_bf16(v0.z, v0.w);
                p.z = pack_bf16(v1.x, v1.y);
                p.w = pack_bf16(v1.z, v1.w);
                af[mi][ks] = as_bfrag(p);
            }
        }
    }

    f4 acc[2][NT];
#pragma unroll
    for (int mi = 0; mi < 2; ++mi)
#pragma unroll
        for (int nt = 0; nt < NT; ++nt) acc[mi][nt] = (f4)0.0f;

#pragma unroll
    for (int nt = 0; nt < NT; ++nt) {
        const u32* wr = Wt + (size_t)(nt * 16 + r15) * 64 + quad * 4;
#pragma unroll
        for (int ks = 0; ks < 4; ++ks) {
            bfrag bf = as_bfrag(*(const uint4*)(wr + ks * 16));
            acc[0][nt] = __builtin_amdgcn_mfma_f32_16x16x32_bf16(bf, af[0][ks], acc[0][nt], 0, 0, 0);
            acc[1][nt] = __builtin_amdgcn_mfma_f32_16x16x32_bf16(bf, af[1][ks], acc[1][nt], 0, 0, 0);
        }
    }

#pragma unroll
    for (int mi = 0; mi < 2; ++mi) {
        int row = rowbase + mi * 16 + r15;
        if (row < n) {
            u32* cp = C + (size_t)row * (OUT / 2);
#pragma unroll
            for (int nt = 0; nt < NT; ++nt) {
                uint2 p;
                p.x = pack_bf16(acc[mi][nt][0], acc[mi][nt][1]);
                p.y = pack_bf16(acc[mi][nt][2], acc[mi][nt][3]);
                *(uint2*)(cp + nt * 8 + quad * 2) = p;
            }
        }
    }
}

// Layer-1 gather: one wave per node, F=128 (2 bf16/lane as dword).
// Chunked edge preload + readlane: decode runs on SALU, w is an SGPR operand.
__global__ __launch_bounds__(256) void gather128(const u32* __restrict__ h,
                                                 const float* __restrict__ dinv,
                                                 const int* __restrict__ row_ptr,
                                                 const u32* __restrict__ ew,
                                                 const float* __restrict__ bias,
                                                 u32* __restrict__ outp, int n) {
    const u32 lane = threadIdx.x & 63;
    const int node = blockIdx.x * 4 + (threadIdx.x >> 6);
    if (node >= n) return;

    const float dd  = dinv[node];
    const int   beg = row_ptr[node];
    const int   end = row_ptr[node + 1];

    u32 sv = h[(u32)node * 64u + lane];
    float2 b = ((const float2*)bias)[lane];
    float acc0 = fmaf(bf_lo(sv) * dd, dd, b.x);
    float acc1 = fmaf(bf_hi(sv) * dd, dd, b.y);

    for (int base = beg; base < end; base += 64) {
        int idx = base + (int)lane;
        u32 ev = ew[(idx < end) ? idx : (end - 1)];
        int m = end - base;
        if (m > 64) m = 64;
        for (int j = 0; j < m; ++j) {
            u32 e = (u32)__builtin_amdgcn_readlane((int)ev, j);   // SGPR
            float w  = dec_w(e);                                  // SALU decode
            u32 off  = (e >> 15) << 6;                            // SALU
            u32 v = h[off + lane];
            acc0 = fmaf(w, bf_lo(v), acc0);
            acc1 = fmaf(w, bf_hi(v), acc1);
        }
    }

    outp[(u32)node * 64u + lane] = pack_bf16(fmaxf(acc0, 0.0f), fmaxf(acc1, 0.0f));
}

// Layer-2 gather: one wave per node, F=64 (1 bf16/lane as ushort). fp32 out.
__global__ __launch_bounds__(256) void gather64(const u16* __restrict__ h16,
                                                const float* __restrict__ dinv,
                                                const int* __restrict__ row_ptr,
                                                const u32* __restrict__ ew,
                                                const float* __restrict__ bias,
                                                float* __restrict__ outp, int n) {
    const u32 lane = threadIdx.x & 63;
    const int node = blockIdx.x * 4 + (threadIdx.x >> 6);
    if (node >= n) return;

    const float dd  = dinv[node];
    const int   beg = row_ptr[node];
    const int   end = row_ptr[node + 1];

    u32 sv = h16[(u32)node * 64u + lane];
    float acc = fmaf(__uint_as_float(sv << 16) * dd, dd, bias[lane]);

    for (int base = beg; base < end; base += 64) {
        int idx = base + (int)lane;
        u32 ev = ew[(idx < end) ? idx : (end - 1)];
        int m = end - base;
        if (m > 64) m = 64;
        for (int j = 0; j < m; ++j) {
            u32 e = (u32)__builtin_amdgcn_readlane((int)ev, j);
            float w  = dec_w(e);
            u32 off  = (e >> 15) << 6;   // row stride: 64 ushorts
            u32 v = h16[off + lane];
            acc = fmaf(w, __uint_as_float(v << 16), acc);
        }
    }

    outp[(u32)node * 64u + lane] = acc;
}

extern "C" void kernel_launch(void* const* d_in, const int* in_sizes, int n_in,
                              void* d_out, int out_size, void* d_ws, size_t ws_size,
                              hipStream_t stream) {
    const float* x  = (const float*)d_in[0];
    const int*   ei = (const int*)d_in[1];
    const float* W1 = (const float*)d_in[2];
    const float* b1 = (const float*)d_in[3];
    const float* W2 = (const float*)d_in[4];
    const float* b2 = (const float*)d_in[5];
    float*       out = (float*)d_out;

    const int n = in_sizes[0] / 128;   // 100000
    const int E = in_sizes[1] / 2;     // 1600000
    const int* srcv = ei;
    const int* dstv = ei + E;

    const int NP = 102400;
    u32* wsd = (u32*)d_ws;
    float* dinv    = (float*)wsd;                        // NP
    int*   row_ptr = (int*)(wsd + NP);                   // NP
    u32*   ew      = wsd + 2 * (size_t)NP;               // E
    u32*   h1u     = ew + E;                             // n*64 (gemm1 C / gather128 in)
    u32*   agg1b   = h1u + (size_t)n * 64;               // n*64 (gather128 out / gemm2 A)
    u32*   W1t     = agg1b + (size_t)n * 64;             // 8192
    u32*   W2t     = W1t + 8192;                         // 4096
    int*   bsum    = (int*)(W2t + 4096);                 // 128
    int*   boff    = bsum + 128;                         // 128
    u32*   h2u     = h1u;                                // gemm2 C: n*32, reuses h1u
    int*   cnt     = (int*)h1u;    // overlay: dead before gemm1 writes h1u
    int*   rank    = (int*)agg1b;  // overlay: dead before gather128 writes agg1b

    const int NB = (n + 1023) / 1024;

    // --- CSR build ---
    zero_i32<<<(n + 255) / 256, 256, 0, stream>>>(cnt, n);
    hist_rank<<<(E + 255) / 256, 256, 0, stream>>>(dstv, cnt, rank, E);
    scan_reduce<<<NB, 1024, 0, stream>>>(cnt, bsum, n);
    scan_partials<<<1, 64, 0, stream>>>(bsum, boff, row_ptr, NB, n);
    scan_apply<<<NB, 1024, 0, stream>>>(cnt, boff, row_ptr, dinv, n);
    place_csr<<<(E + 255) / 256, 256, 0, stream>>>(srcv, dstv, rank, row_ptr, dinv, ew, E);

    // --- weights to bf16, transposed ---
    prep_w<<<48, 256, 0, stream>>>(W1, W2, W1t, W2t);

    const int gblocks = (n + 127) / 128;  // 782
    // --- layer 1 ---
    gemm_mfma<128, false><<<gblocks, 256, 0, stream>>>(x, W1t, h1u, n);
    gather128<<<(n + 3) / 4, 256, 0, stream>>>(h1u, dinv, row_ptr, ew, b1, agg1b, n);

    // --- layer 2 ---
    gemm_mfma<64, true><<<gblocks, 256, 0, stream>>>(agg1b, W2t, h2u, n);
    gather64<<<(n + 3) / 4, 256, 0, stream>>>((const u16*)h2u, dinv, row_ptr, ew, b2, out, n);
}